// Round 4
// baseline (181.111 us; speedup 1.0000x reference)
//
#include <hip/hip_runtime.h>

// Problem: B=8, L=2048, H=256. fp32 in/out.
#define B_ 8
#define L_ 2048
#define H_ 256
#define LOG2E 1.4426950408889634f

typedef _Float16 half8 __attribute__((ext_vector_type(8)));
typedef _Float16 half4_t __attribute__((ext_vector_type(4)));
typedef float f32x4 __attribute__((ext_vector_type(4)));

__device__ __forceinline__ float fast_tanh(float x) {
    const float e2 = __expf(2.f * x);
    return 1.f - 2.f * __builtin_amdgcn_rcpf(e2 + 1.f);
}

// ---------------------------------------------------------------------------
// prep: one block = 64 rows of text (mat=0) or opin (mat=1).
// MFMA GEMM rows@W^T (fp16 in, fp32 acc), W chunks double-buffered in LDS with
// register prefetch (1 barrier/chunk). Epilogue tanh/wa reduce.
// mat=1 also emits V^T fp16 in CHUNK-TILED layout: vtg[((b*32+chunk)*256+h)*64+jj].
// ---------------------------------------------------------------------------
__global__ __launch_bounds__(256, 2) void prep_kernel(
    const float* __restrict__ opin, const float* __restrict__ text,
    const int* __restrict__ pos_ids,
    const float* __restrict__ Wt, const float* __restrict__ bt,
    const float* __restrict__ Wo, const float* __restrict__ wa,
    const float* __restrict__ ba,
    float* __restrict__ ws_st, float2* __restrict__ ws_cm,
    _Float16* __restrict__ vtg)
{
    __shared__ __align__(16) _Float16 a_lds[4][8][512];   // [rowgrp][kchunk][frag-linear]
    __shared__ __align__(16) _Float16 w_lds[2][16][512];  // double-buffered W chunk

    const int tid  = threadIdx.x;
    const int lane = tid & 63;
    const int rg   = tid >> 6;
    const int mat  = blockIdx.x & 1;                    // 0=text, 1=opin
    const size_t g0 = (size_t)(blockIdx.x >> 1) * 64;   // first flattened row (b*L+i)

    const float* __restrict__ src = mat ? opin : text;
    const float* __restrict__ W   = mat ? Wo   : Wt;

    // ---- stage A: 64 rows x 256 k, fp32 -> fp16, frag-linear per (rg, kc) ----
#pragma unroll
    for (int v = 0; v < 16; ++v) {
        const int idx = v * 256 + tid;
        const int row = idx >> 6;
        const int k   = (idx & 63) * 4;
        const float4 f = *(const float4*)(src + (g0 + row) * 256 + k);
        half4_t h = { (_Float16)f.x, (_Float16)f.y, (_Float16)f.z, (_Float16)f.w };
        const int off = ((row & 15) + 16 * ((k >> 3) & 3)) * 8 + (k & 7);
        *(half4_t*)&a_lds[row >> 4][k >> 5][off] = h;
    }

    // prefetch W chunk 0 into registers
    float4 wreg[8];
    const int wn_base = tid >> 3;          // +p*32
    const int wk      = (tid & 7) * 4;
#pragma unroll
    for (int p = 0; p < 8; ++p)
        wreg[p] = *(const float4*)(W + (p * 32 + wn_base) * 256 + 0 * 32 + wk);

    __syncthreads();   // A staged

    f32x4 acc[16];
#pragma unroll
    for (int nt = 0; nt < 16; ++nt) acc[nt] = (f32x4){0.f, 0.f, 0.f, 0.f};

    for (int kc = 0; kc < 8; ++kc) {
        // write prefetched W chunk to w_lds[kc&1]
#pragma unroll
        for (int p = 0; p < 8; ++p) {
            const int n = p * 32 + wn_base;
            half4_t h = { (_Float16)wreg[p].x, (_Float16)wreg[p].y,
                          (_Float16)wreg[p].z, (_Float16)wreg[p].w };
            const int off = ((n & 15) + 16 * (wk >> 3)) * 8 + (wk & 7);
            *(half4_t*)&w_lds[kc & 1][n >> 4][off] = h;
        }
        __syncthreads();
        if (kc + 1 < 8) {
#pragma unroll
            for (int p = 0; p < 8; ++p)
                wreg[p] = *(const float4*)(W + (p * 32 + wn_base) * 256 + (kc + 1) * 32 + wk);
        }
        const half8 afrag = *(const half8*)&a_lds[rg][kc][lane * 8];
#pragma unroll
        for (int nt = 0; nt < 16; ++nt) {
            const half8 bfrag = *(const half8*)&w_lds[kc & 1][nt][lane * 8];
            acc[nt] = __builtin_amdgcn_mfma_f32_16x16x32_f16(afrag, bfrag, acc[nt], 0, 0, 0);
        }
    }

    // ---- epilogue: rowsum_n( tanh(acc + bt?) * wa ) ----
    const int em = lane & 15, q = lane >> 4;
    float rowsum[4] = {0.f, 0.f, 0.f, 0.f};
#pragma unroll
    for (int nt = 0; nt < 16; ++nt) {
        const int col  = nt * 16 + em;
        const float btv = mat ? 0.f : bt[col];
        const float wav = wa[mat * 256 + col];
#pragma unroll
        for (int r = 0; r < 4; ++r)
            rowsum[r] += fast_tanh(acc[nt][r] + btv) * wav;
    }
#pragma unroll
    for (int r = 0; r < 4; ++r) {
        float s = rowsum[r];
        s += __shfl_xor(s, 1, 64);
        s += __shfl_xor(s, 2, 64);
        s += __shfl_xor(s, 4, 64);
        s += __shfl_xor(s, 8, 64);
        if (em == 0) {
            const size_t grow = g0 + rg * 16 + q * 4 + r;
            if (mat == 0) {
                ws_st[grow] = s;
            } else {
                const int p = pos_ids[grow];
                const bool isop = (p==19)|(p==20)|(p==21)|(p==33)|(p==34)|(p==35)|((p>=41)&(p<=46));
                const float mult = isop ? 8.f : 1.f;
                ws_cm[grow] = make_float2((s + ba[0]) * mult, mult);
            }
        }
    }

    // ---- V^T emission (opin blocks), chunk-tiled: [(b*32+chunk)*256+h][64 j] ----
    if (mat == 1) {
        const int h = tid;
        const size_t b = g0 >> 11;
        const int chunk = (int)((g0 & 2047) >> 6);
        const int kcS = h >> 5, kq = (h >> 3) & 3, jh = h & 7;
        _Float16 vals[64];
#pragma unroll
        for (int r = 0; r < 64; ++r)
            vals[r] = a_lds[r >> 4][kcS][((r & 15) + 16 * kq) * 8 + jh];
        _Float16* dst = vtg + ((b * 32 + chunk) * 256 + h) * 64;
#pragma unroll
        for (int w = 0; w < 8; ++w)
            *(half8*)(dst + w * 8) = *(half8*)&vals[w * 8];
    }
}

// ---------------------------------------------------------------------------
// attn: 256 blocks = (b, 64-row i-tile), full 256 h per block. 4 waves:
// (rowg -> 32 rows as 2 rt tiles, hh -> 128 h-cols as 8 ht tiles).
// Exact row-max prepass in-block (LDS bl/cm tables). K-loop: A-frags (P)
// computed directly in registers, V^T double-buffered LDS, 1 barrier/chunk.
// All score math in log2 domain: s' = fma(st, m, cm)*bl[d], p = exp2(s'-m').
// ---------------------------------------------------------------------------
__global__ __launch_bounds__(256, 1) void attn_kernel(
    const float* __restrict__ ws_st, const float2* __restrict__ ws_cm,
    const _Float16* __restrict__ vtg, float* __restrict__ out)
{
    __shared__ float  bl[2048];                     // base(d) * log2e
    __shared__ __align__(16) float2 cm[2048];       // {c*mult, mult}
    __shared__ float  m_tbl[64];
    __shared__ __align__(16) _Float16 vt[2][256 * 64];  // V^T dbuf, XOR-swizzled

    const int tid  = threadIdx.x;
    const int lane = tid & 63;
    const int wid  = tid >> 6;
    const int rowg = wid & 1;
    const int hh   = wid >> 1;
    const int em   = lane & 15;
    const int quad = lane >> 4;
    const int b    = blockIdx.x & 7;
    const int i0   = (blockIdx.x >> 3) * 64;

    // ---- stage tables ----
#pragma unroll
    for (int v = 0; v < 8; ++v) {
        const int d = v * 256 + tid;
        bl[d] = (d == 0) ? 0.5f * LOG2E : LOG2E / log2f(2.0f + (float)d);
    }
#pragma unroll
    for (int v = 0; v < 4; ++v) {   // 2048 float2 = 1024 float4
        const int idx = v * 256 + tid;
        *(((float4*)cm) + idx) = *(((const float4*)(ws_cm + b * 2048)) + idx);
    }

    // ---- prefetch V^T chunk 0 (latency hidden behind prepass) ----
    const _Float16* vsrc_base = vtg + (size_t)(b * 32) * 256 * 64;
    half8 vr[8];
#pragma unroll
    for (int i = 0; i < 8; ++i)
        vr[i] = *(const half8*)(vsrc_base + (size_t)(i * 256 + tid) * 8);

    __syncthreads();   // tables ready

    // ---- exact row-max prepass: wave wid -> rows wid*16..+15 ----
    {
        const int prow_l = wid * 16 + (lane >> 2);         // local row in tile
        const int gi_p   = i0 + prow_l;
        const float st_p = ws_st[b * 2048 + gi_p];
        const int jg = (lane & 3) * 8;
        float mx = -3.0e38f;
        for (int t = 0; t < 64; ++t) {
            const int j = t * 32 + jg;
            const float4 c01 = *(const float4*)&cm[j];
            const float4 c23 = *(const float4*)&cm[j + 2];
            const float4 c45 = *(const float4*)&cm[j + 4];
            const float4 c67 = *(const float4*)&cm[j + 6];
            const float cmm[8] = {c01.x, c01.z, c23.x, c23.z, c45.x, c45.z, c67.x, c67.z};
            const float mm[8]  = {c01.y, c01.w, c23.y, c23.w, c45.y, c45.w, c67.y, c67.w};
#pragma unroll
            for (int e = 0; e < 8; ++e) {
                int d = gi_p - (j + e); d = d < 0 ? -d : d;
                const float s = fmaf(st_p, mm[e], cmm[e]) * bl[d];
                mx = fmaxf(mx, s);
            }
        }
        mx = fmaxf(mx, __shfl_xor(mx, 1, 64));
        mx = fmaxf(mx, __shfl_xor(mx, 2, 64));
        if ((lane & 3) == 0) m_tbl[prow_l] = mx;
    }
    __syncthreads();   // m_tbl ready

    // ---- per-lane row constants ----
    float st_r[2], mp[2];
#pragma unroll
    for (int rt = 0; rt < 2; ++rt) {
        const int rloc = rowg * 32 + rt * 16 + em;
        st_r[rt] = ws_st[b * 2048 + i0 + rloc];
        mp[rt]   = m_tbl[rloc];
    }
    const int gi0 = i0 + rowg * 32 + em;   // rt=0 global row; rt=1 adds 16

    f32x4 acc[2][8];
#pragma unroll
    for (int rt = 0; rt < 2; ++rt)
#pragma unroll
        for (int ht = 0; ht < 8; ++ht) acc[rt][ht] = (f32x4){0.f, 0.f, 0.f, 0.f};
    float zacc[2] = {0.f, 0.f};

    const int st_h  = tid >> 3;            // staging: h = i*32 + st_h
    const int st_jb = tid & 7;

    // ---- main K loop: 1 barrier per chunk ----
    for (int kc = 0; kc < 32; ++kc) {
        const int buf = kc & 1;
        // write prefetched chunk to vt[buf] (swizzled)
#pragma unroll
        for (int i = 0; i < 8; ++i) {
            const int h = i * 32 + st_h;
            *(half8*)&vt[buf][h * 64 + ((st_jb ^ (h & 7)) * 8)] = vr[i];
        }
        __syncthreads();
        // prefetch next chunk
        if (kc + 1 < 32) {
            const _Float16* vsrc = vsrc_base + (size_t)(kc + 1) * 256 * 64;
#pragma unroll
            for (int i = 0; i < 8; ++i)
                vr[i] = *(const half8*)(vsrc + (size_t)(i * 256 + tid) * 8);
        }
        // scores -> A-fragments in registers
        const int j0 = kc * 64;
        half8 af[2][2];
#pragma unroll
        for (int ks = 0; ks < 2; ++ks) {
            const int jbase = j0 + ks * 32 + quad * 8;
            const float4 c01 = *(const float4*)&cm[jbase];
            const float4 c23 = *(const float4*)&cm[jbase + 2];
            const float4 c45 = *(const float4*)&cm[jbase + 4];
            const float4 c67 = *(const float4*)&cm[jbase + 6];
            const float cmm[8] = {c01.x, c01.z, c23.x, c23.z, c45.x, c45.z, c67.x, c67.z};
            const float mm[8]  = {c01.y, c01.w, c23.y, c23.w, c45.y, c45.w, c67.y, c67.w};
            float blv[8];
#pragma unroll
            for (int e = 0; e < 8; ++e) {
                int d0 = gi0 - (jbase + e); d0 = d0 < 0 ? -d0 : d0;
                blv[e] = bl[d0];                      // rt=0 distance
            }
#pragma unroll
            for (int rt = 0; rt < 2; ++rt) {
#pragma unroll
                for (int e = 0; e < 8; ++e) {
                    int d = (gi0 + rt * 16) - (jbase + e); d = d < 0 ? -d : d;
                    const float blr = rt ? bl[d] : blv[e];
                    const float s = fmaf(st_r[rt], mm[e], cmm[e]) * blr - mp[rt];
                    const float p = __builtin_exp2f(s);
                    zacc[rt] += p;
                    af[rt][ks][e] = (_Float16)p;
                }
            }
        }
        // MFMA: B-frags read once, reused across rt
#pragma unroll
        for (int ht = 0; ht < 8; ++ht) {
            const int hcol = hh * 128 + ht * 16 + em;
            const int hb = hcol * 64, sw = hcol & 7;
            const half8 b0 = *(const half8*)&vt[buf][hb + ((quad ^ sw) * 8)];
            const half8 b1 = *(const half8*)&vt[buf][hb + (((4 + quad) ^ sw) * 8)];
            acc[0][ht] = __builtin_amdgcn_mfma_f32_16x16x32_f16(af[0][0], b0, acc[0][ht], 0, 0, 0);
            acc[0][ht] = __builtin_amdgcn_mfma_f32_16x16x32_f16(af[0][1], b1, acc[0][ht], 0, 0, 0);
            acc[1][ht] = __builtin_amdgcn_mfma_f32_16x16x32_f16(af[1][0], b0, acc[1][ht], 0, 0, 0);
            acc[1][ht] = __builtin_amdgcn_mfma_f32_16x16x32_f16(af[1][1], b1, acc[1][ht], 0, 0, 0);
        }
    }

    // ---- Z finalize (per-wave complete) + epilogue ----
    float rz[2][4];
#pragma unroll
    for (int rt = 0; rt < 2; ++rt) {
        float z = zacc[rt];
        z += __shfl_xor(z, 16, 64);
        z += __shfl_xor(z, 32, 64);       // every lane: Z for row em of this rt
#pragma unroll
        for (int r = 0; r < 4; ++r)
            rz[rt][r] = 1.0f / __shfl(z, quad * 4 + r, 64);
    }
#pragma unroll
    for (int rt = 0; rt < 2; ++rt) {
#pragma unroll
        for (int r = 0; r < 4; ++r) {
            const int row = i0 + rowg * 32 + rt * 16 + quad * 4 + r;
            float* op = out + ((size_t)b * 2048 + row) * 256 + hh * 128 + em;
#pragma unroll
            for (int ht = 0; ht < 8; ++ht)
                op[ht * 16] = acc[rt][ht][r] * rz[rt][r];
        }
    }
}

// ---------------------------------------------------------------------------
extern "C" void kernel_launch(void* const* d_in, const int* in_sizes, int n_in,
                              void* d_out, int out_size, void* d_ws, size_t ws_size,
                              hipStream_t stream) {
    const float* opin  = (const float*)d_in[0];
    const float* text  = (const float*)d_in[1];
    const int* pos_ids = (const int*)d_in[2];
    const float* Wt    = (const float*)d_in[3];
    const float* bt    = (const float*)d_in[4];
    const float* Wo    = (const float*)d_in[5];
    const float* wa    = (const float*)d_in[6];
    const float* ba    = (const float*)d_in[7];
    float* out         = (float*)d_out;

    // workspace: st (64 KB) | cm (128 KB) | vtg fp16 chunk-tiled (8 MB)
    float*  ws_st = (float*)d_ws;
    float2* ws_cm = (float2*)((char*)d_ws + 65536);
    _Float16* vtg = (_Float16*)((char*)d_ws + 65536 + 131072);

    prep_kernel<<<512, 256, 0, stream>>>(opin, text, pos_ids, Wt, bt, Wo, wa, ba,
                                         ws_st, ws_cm, vtg);
    attn_kernel<<<256, 256, 0, stream>>>(ws_st, ws_cm, vtg, out);
}